// Round 1
// baseline (2162.615 us; speedup 1.0000x reference)
//
#include <hip/hip_runtime.h>

// Problem dims (fixed)
#define Bc 128   // batch
#define Tc 128   // timesteps
#define Nc 128   // driving series
#define Mc 256   // hidden
#define G4 1024  // 4*M

__device__ __forceinline__ float frcp(float x) {
#if __has_builtin(__builtin_amdgcn_rcpf)
  return __builtin_amdgcn_rcpf(x);
#else
  return 1.f / x;
#endif
}
__device__ __forceinline__ float fsig(float x) { return frcp(1.f + __expf(-x)); }
__device__ __forceinline__ float ftanh(float x) {
  // tanh(x) = 1 - 2/(exp(2x)+1); saturates correctly at +/-inf
  float t = __expf(2.f * x);
  return 1.f - 2.f * frcp(t + 1.f);
}

// K1: UXT[b][u][n] = sum_t X[b][t][n] * Ud[t][u] + bU[u]   (transposed for coalesced K5 reads)
__global__ void k_ux(const float* __restrict__ X, const float* __restrict__ Ud,
                     const float* __restrict__ bU, float* __restrict__ UXT) {
  __shared__ float Xl[Tc][Nc];  // 64KB
  int b = blockIdx.x;
  const float* Xb = X + (size_t)b * Tc * Nc;
  for (int i = threadIdx.x; i < Tc * Nc; i += 256) Xl[i >> 7][i & 127] = Xb[i];
  __syncthreads();
  int n = threadIdx.x & 127;
  int uh = __builtin_amdgcn_readfirstlane(threadIdx.x >> 7);  // u-half, wave-uniform
  for (int u0 = uh * 64; u0 < uh * 64 + 64; u0 += 8) {
    float acc[8];
#pragma unroll
    for (int i = 0; i < 8; i++) acc[i] = 0.f;
    for (int tt = 0; tt < Tc; ++tt) {
      float xv = Xl[tt][n];
#pragma unroll
      for (int i = 0; i < 8; i++) acc[i] += xv * Ud[tt * Tc + u0 + i];  // uniform -> s_load
    }
#pragma unroll
    for (int i = 0; i < 8; i++)
      UXT[((size_t)b * Tc + (u0 + i)) * Nc + n] = acc[i] + bU[u0 + i];
  }
}

// K2: XWx[t][b][j] = sum_n X[b][t][n] * Wx[n][j] + b[j]
__global__ void k_xwx(const float* __restrict__ X, const float* __restrict__ Wx,
                      const float* __restrict__ bias, float* __restrict__ XWx) {
  __shared__ float xl[16][Nc];  // 8KB: 16 rows (same t, 16 consecutive b)
  int r0 = blockIdx.x * 16;
  int t = r0 >> 7, b0 = r0 & 127;
  for (int i = threadIdx.x; i < 16 * Nc; i += 256) {
    int row = i >> 7, n = i & 127;
    xl[row][n] = X[(size_t)(b0 + row) * Tc * Nc + (size_t)t * Nc + n];
  }
  __syncthreads();
  int c0 = threadIdx.x * 4;
  float acc[16][4];
#pragma unroll
  for (int i = 0; i < 16; i++)
#pragma unroll
    for (int k = 0; k < 4; k++) acc[i][k] = 0.f;
  for (int n = 0; n < Nc; ++n) {
    float4 w = *(const float4*)(Wx + (size_t)n * G4 + c0);
#pragma unroll
    for (int i = 0; i < 16; i++) {
      float xv = xl[i][n];
      acc[i][0] += xv * w.x; acc[i][1] += xv * w.y;
      acc[i][2] += xv * w.z; acc[i][3] += xv * w.w;
    }
  }
  float4 bb = *(const float4*)(bias + c0);
#pragma unroll
  for (int i = 0; i < 16; i++) {
    float4 o;
    o.x = acc[i][0] + bb.x; o.y = acc[i][1] + bb.y;
    o.z = acc[i][2] + bb.z; o.w = acc[i][3] + bb.w;
    *(float4*)(XWx + ((size_t)t * Bc + b0 + i) * G4 + c0) = o;
  }
}

// K3: one LSTM step. grid (16 bg, 8 q), block 256.
// Each block: 8 batches x 128 cols (its mo-slice across all 4 gates), full K=256.
__global__ void k_step(const float* __restrict__ XWx, const float* __restrict__ Wh,
                       const float* __restrict__ hprev, const float* __restrict__ cprev,
                       float* __restrict__ Hout, float* __restrict__ Cout, int t) {
  __shared__ float zl[128][8];  // 4KB
  int bg = blockIdx.x, q = blockIdx.y;
  int c = threadIdx.x & 127;                                      // local col
  int halfm = threadIdx.x >> 7;                                   // m-half (wave-uniform)
  int m0 = __builtin_amdgcn_readfirstlane((threadIdx.x >> 7) * 128);
  int g = c >> 5, mo = c & 31;
  int j = g * Mc + q * 32 + mo;                                   // global col in [0,1024)
  const float* whcol = Wh + j;
  float acc[8];
#pragma unroll
  for (int i = 0; i < 8; i++) acc[i] = 0.f;
#pragma unroll 4
  for (int m4 = 0; m4 < 32; ++m4) {
    int m = m0 + m4 * 4;
    float w0 = whcol[(size_t)(m + 0) * G4];
    float w1 = whcol[(size_t)(m + 1) * G4];
    float w2 = whcol[(size_t)(m + 2) * G4];
    float w3 = whcol[(size_t)(m + 3) * G4];
#pragma unroll
    for (int i = 0; i < 8; i++) {
      const float4 hv = *(const float4*)(hprev + (size_t)(bg * 8 + i) * Mc + m);  // uniform -> s_load
      acc[i] += w0 * hv.x + w1 * hv.y + w2 * hv.z + w3 * hv.w;
    }
  }
  if (halfm == 1) {
#pragma unroll
    for (int i = 0; i < 8; i++) zl[c][i] = acc[i];
  }
  __syncthreads();
  if (halfm == 0) {
#pragma unroll
    for (int i = 0; i < 8; i++) {
      float z = acc[i] + zl[c][i] + XWx[((size_t)t * Bc + bg * 8 + i) * G4 + j];
      zl[c][i] = z;  // same thread owns zl[c][*]: read-then-write is safe
    }
  }
  __syncthreads();
  // gates: 256 threads = 8 batches x 32 mo
  int lb = threadIdx.x >> 5, mo2 = threadIdx.x & 31;
  int b = bg * 8 + lb;
  int mog = q * 32 + mo2;
  float zi = zl[mo2][lb];
  float zf = zl[32 + mo2][lb];
  float zg = zl[64 + mo2][lb];
  float zo = zl[96 + mo2][lb];
  float cold = cprev[(size_t)b * Mc + mog];
  float i_ = fsig(zi), f_ = fsig(zf), g_ = ftanh(zg), o_ = fsig(zo);
  float cn = f_ * cold + i_ * g_;
  float hn = o_ * ftanh(cn);
  Hout[(size_t)b * Mc + mog] = hn;
  Cout[(size_t)b * Mc + mog] = cn;
}

// K4: Wall[t*B+b][u] = sum_k [H|C][t,b,k] * Wd[k][u] + bW[u]
__global__ void k_wall(const float* __restrict__ H, const float* __restrict__ Cs,
                       const float* __restrict__ Wd, const float* __restrict__ bW,
                       float* __restrict__ Wall) {
  int r0 = blockIdx.x * 32;
  int wv = __builtin_amdgcn_readfirstlane(threadIdx.x >> 6);
  int lane = threadIdx.x & 63;
  int u2 = lane * 2;
  int rbase = r0 + wv * 8;
  float acc[8][2];
#pragma unroll
  for (int i = 0; i < 8; i++) { acc[i][0] = 0.f; acc[i][1] = 0.f; }
#pragma unroll 4
  for (int k = 0; k < Mc; ++k) {
    float2 wd = *(const float2*)(Wd + (size_t)k * Tc + u2);
#pragma unroll
    for (int i = 0; i < 8; i++) {
      float hv = H[(size_t)(rbase + i) * Mc + k];  // uniform -> s_load
      acc[i][0] += hv * wd.x; acc[i][1] += hv * wd.y;
    }
  }
#pragma unroll 4
  for (int k = 0; k < Mc; ++k) {
    float2 wd = *(const float2*)(Wd + (size_t)(k + Mc) * Tc + u2);
#pragma unroll
    for (int i = 0; i < 8; i++) {
      float cv = Cs[(size_t)(rbase + i) * Mc + k];
      acc[i][0] += cv * wd.x; acc[i][1] += cv * wd.y;
    }
  }
  float bw0 = bW[u2], bw1 = bW[u2 + 1];
#pragma unroll
  for (int i = 0; i < 8; i++) {
    float2 o; o.x = acc[i][0] + bw0; o.y = acc[i][1] + bw1;
    *(float2*)(Wall + (size_t)(rbase + i) * Tc + u2) = o;
  }
}

// K5: e -> softmax over n -> out = X * alpha. Block = 2 rows (t,b).
__global__ void k_attn(const float* __restrict__ Wall, const float* __restrict__ UXT,
                       const float* __restrict__ vd, const float* __restrict__ X,
                       float* __restrict__ out) {
  __shared__ float wl[2][Nc];
  __shared__ float vl[Nc];
  __shared__ float rmax[4], rsum[4];
  int r0 = blockIdx.x * 2;
  int rr = threadIdx.x >> 7, n = threadIdx.x & 127;
  if (threadIdx.x < Nc) vl[threadIdx.x] = vd[threadIdx.x];
  wl[rr][n] = Wall[(size_t)(r0 + rr) * Tc + n];
  __syncthreads();
  int r = r0 + rr;
  int t = r >> 7, b = r & 127;
  const float* uxb = UXT + (size_t)b * Tc * Nc;  // [u][n]
  float e = 0.f;
#pragma unroll 4
  for (int u = 0; u < Tc; ++u) {
    float s = wl[rr][u] + uxb[(size_t)u * Nc + n];
    e += ftanh(s) * vl[u];
  }
  // softmax over the 128 lanes of this row (2 waves)
  float m = e;
#pragma unroll
  for (int off = 32; off > 0; off >>= 1) m = fmaxf(m, __shfl_xor(m, off));
  int wv = threadIdx.x >> 6;
  if ((threadIdx.x & 63) == 0) rmax[wv] = m;
  __syncthreads();
  float mrow = fmaxf(rmax[rr * 2], rmax[rr * 2 + 1]);
  float ex = __expf(e - mrow);
  float s = ex;
#pragma unroll
  for (int off = 32; off > 0; off >>= 1) s += __shfl_xor(s, off);
  if ((threadIdx.x & 63) == 0) rsum[wv] = s;
  __syncthreads();
  float srow = rsum[rr * 2] + rsum[rr * 2 + 1];
  float alpha = ex * frcp(srow);
  size_t xi = ((size_t)b * Tc + t) * Nc + n;
  out[xi] = X[xi] * alpha;
}

extern "C" void kernel_launch(void* const* d_in, const int* in_sizes, int n_in,
                              void* d_out, int out_size, void* d_ws, size_t ws_size,
                              hipStream_t stream) {
  (void)in_sizes; (void)n_in; (void)out_size; (void)ws_size;
  const float* X  = (const float*)d_in[0];
  const float* h0 = (const float*)d_in[1];
  const float* s0 = (const float*)d_in[2];
  const float* Wx = (const float*)d_in[3];
  const float* Wh = (const float*)d_in[4];
  const float* bb = (const float*)d_in[5];
  const float* Wd = (const float*)d_in[6];
  const float* bW = (const float*)d_in[7];
  const float* Ud = (const float*)d_in[8];
  const float* bU = (const float*)d_in[9];
  const float* vd = (const float*)d_in[10];
  // d_in[11] = bv: softmax(x + const) == softmax(x), no effect on output.
  float* out = (float*)d_out;
  float* ws = (float*)d_ws;

  float* UXT  = ws;                      // B*T*N        = 2,097,152 f
  float* XWx  = UXT + 2097152;           // T*B*4M       = 16,777,216 f
  float* H    = XWx + 16777216;          // T*B*M        = 4,194,304 f
  float* C    = H + 4194304;             // T*B*M        = 4,194,304 f
  float* Wall = C + 4194304;             // T*B*T        = 2,097,152 f
                                         // total ~117.4 MB

  k_ux<<<Bc, 256, 0, stream>>>(X, Ud, bU, UXT);
  k_xwx<<<(Tc * Bc) / 16, 256, 0, stream>>>(X, Wx, bb, XWx);
  for (int t = 0; t < Tc; ++t) {
    const float* hp = t ? (H + (size_t)(t - 1) * Bc * Mc) : h0;
    const float* cp = t ? (C + (size_t)(t - 1) * Bc * Mc) : s0;
    k_step<<<dim3(16, 8), 256, 0, stream>>>(XWx, Wh, hp, cp,
                                            H + (size_t)t * Bc * Mc,
                                            C + (size_t)t * Bc * Mc, t);
  }
  k_wall<<<(Tc * Bc) / 32, 256, 0, stream>>>(H, C, Wd, bW, Wall);
  k_attn<<<(Tc * Bc) / 2, 256, 0, stream>>>(Wall, UXT, vd, X, out);
}

// Round 2
// 1159.291 us; speedup vs baseline: 1.8655x; 1.8655x over previous
//
#include <hip/hip_runtime.h>
#include <hip/hip_fp16.h>

// Problem dims (fixed)
#define Bc 128   // batch
#define Tc 128   // timesteps
#define Nc 128   // driving series
#define Mc 256   // hidden
#define G4 1024  // 4*M

typedef _Float16 half8 __attribute__((ext_vector_type(8)));
typedef float f32x4 __attribute__((ext_vector_type(4)));

__device__ __forceinline__ float frcp(float x) {
#if __has_builtin(__builtin_amdgcn_rcpf)
  return __builtin_amdgcn_rcpf(x);
#else
  return 1.f / x;
#endif
}
__device__ __forceinline__ float fsig(float x) { return frcp(1.f + __expf(-x)); }
__device__ __forceinline__ float ftanh(float x) {
  float t = __expf(2.f * x);
  return 1.f - 2.f * frcp(t + 1.f);
}

// ---------------------------------------------------------------------------
// k_prep: (a) pack Wh (fp32, [256][1024]) into fp16 MFMA A-fragments with the
// gate-interleaved column permutation j' = 4*mcol + g;
// layout: wht[jt(64)][kt(8)][lane(64)][reg(8)] halves,
//   value = Wh[kt*32 + (lane>>4)*8 + reg][g*256 + mcol], j' = jt*16 + (lane&15)
// (b) zero the flag counters; (c) hx[0] = fp16(h0).
// ---------------------------------------------------------------------------
__global__ void k_prep(const float* __restrict__ Wh, const float* __restrict__ h0,
                       __half* __restrict__ wht, __half* __restrict__ hx,
                       unsigned* __restrict__ flags) {
  int bid = blockIdx.x;
  if (bid < 512) {
    int i = bid * 256 + threadIdx.x;       // u32 index in [0, 131072)
    int jt = i >> 11;
    int rem = i & 2047;
    int kt = rem >> 8;
    int rem2 = rem & 255;
    int lane = rem2 >> 2;
    int r2 = rem2 & 3;                     // regs 2*r2, 2*r2+1
    int jp = jt * 16 + (lane & 15);        // permuted col j'
    int g = jp & 3, mcol = jp >> 2;
    int j = g * 256 + mcol;                // original Wh column
    int mk0 = kt * 32 + (lane >> 4) * 8 + 2 * r2;
    wht[(size_t)i * 2]     = __float2half(Wh[(size_t)mk0 * G4 + j]);
    wht[(size_t)i * 2 + 1] = __float2half(Wh[(size_t)(mk0 + 1) * G4 + j]);
  } else {
    // flags (8 groups x 132) = 1056 u32
    for (int i = threadIdx.x; i < 8 * 132; i += 256) flags[i] = 0u;
    // hx[0] = fp16(h0): 32768 halves
    for (int i = threadIdx.x; i < Bc * Mc; i += 256) hx[i] = __float2half(h0[i]);
  }
}

// ---------------------------------------------------------------------------
// k_ux: UXT[b][u][n] = sum_t X[b][t][n] * Ud[t][u] + bU[u]
// ---------------------------------------------------------------------------
__global__ void k_ux(const float* __restrict__ X, const float* __restrict__ Ud,
                     const float* __restrict__ bU, float* __restrict__ UXT) {
  __shared__ float Xl[Tc][Nc];  // 64KB
  int b = blockIdx.x;
  const float* Xb = X + (size_t)b * Tc * Nc;
  for (int i = threadIdx.x; i < Tc * Nc; i += 256) Xl[i >> 7][i & 127] = Xb[i];
  __syncthreads();
  int n = threadIdx.x & 127;
  int uh = __builtin_amdgcn_readfirstlane(threadIdx.x >> 7);
  for (int u0 = uh * 64; u0 < uh * 64 + 64; u0 += 8) {
    float acc[8];
#pragma unroll
    for (int i = 0; i < 8; i++) acc[i] = 0.f;
    for (int tt = 0; tt < Tc; ++tt) {
      float xv = Xl[tt][n];
#pragma unroll
      for (int i = 0; i < 8; i++) acc[i] += xv * Ud[tt * Tc + u0 + i];
    }
#pragma unroll
    for (int i = 0; i < 8; i++)
      UXT[((size_t)b * Tc + (u0 + i)) * Nc + n] = acc[i] + bU[u0 + i];
  }
}

// ---------------------------------------------------------------------------
// k_xwx2: XWxP[t][b][j'] = sum_n X[b][t][n]*Wx[n][j(j')] + bias[j(j')],
// stored with the gate-interleaved permutation j' = 4m+g.
// grid: 1024 blocks = t(128) x bgroup(8), 256 threads = m.
// ---------------------------------------------------------------------------
__global__ void k_xwx2(const float* __restrict__ X, const float* __restrict__ Wx,
                       const float* __restrict__ bias, float* __restrict__ XWxP) {
  __shared__ float xl[16][Nc];  // 8KB
  int t = blockIdx.x >> 3;
  int b0 = (blockIdx.x & 7) * 16;
  for (int i = threadIdx.x; i < 16 * Nc; i += 256) {
    int row = i >> 7, n = i & 127;
    xl[row][n] = X[(size_t)(b0 + row) * Tc * Nc + (size_t)t * Nc + n];
  }
  __syncthreads();
  int m = threadIdx.x;
  float acc[16][4];
#pragma unroll
  for (int i = 0; i < 16; i++)
#pragma unroll
    for (int g = 0; g < 4; g++) acc[i][g] = 0.f;
  for (int n = 0; n < Nc; ++n) {
    float wi = Wx[(size_t)n * G4 + m];
    float wf = Wx[(size_t)n * G4 + 256 + m];
    float wg = Wx[(size_t)n * G4 + 512 + m];
    float wo = Wx[(size_t)n * G4 + 768 + m];
#pragma unroll
    for (int i = 0; i < 16; i++) {
      float xv = xl[i][n];
      acc[i][0] += xv * wi; acc[i][1] += xv * wf;
      acc[i][2] += xv * wg; acc[i][3] += xv * wo;
    }
  }
  float bi = bias[m], bf = bias[256 + m], bg = bias[512 + m], bo = bias[768 + m];
#pragma unroll
  for (int i = 0; i < 16; i++) {
    float4 o;
    o.x = acc[i][0] + bi; o.y = acc[i][1] + bf;
    o.z = acc[i][2] + bg; o.w = acc[i][3] + bo;
    *(float4*)(XWxP + ((size_t)t * Bc + b0 + i) * G4 + m * 4) = o;
  }
}

// ---------------------------------------------------------------------------
// k_scan: persistent LSTM scan. 32 blocks x 512 threads.
// bid = q*8 + grp  (grp in 0..7: batch group of 16; q in 0..3: m-quarter)
// Each block: batches grp*16..+15, columns j' in [q*256, q*256+256)
//   = m in [q*64, q*64+64), all 4 gates.  Wh A-frags held in VGPRs.
// Per step: B-frags (h) from hx[t]; acc init from XWxP; 16 MFMA; gates on
// regs; h -> hx[t+1] (fp16), c -> cx[t] (fp16); release-inc group flag;
// next step acquire-polls flag==4.
// ---------------------------------------------------------------------------
__global__ __launch_bounds__(512, 2)
void k_scan(const __half* __restrict__ wht, const float* __restrict__ xwxp,
            __half* __restrict__ hx, __half* __restrict__ cx,
            unsigned* __restrict__ flags, const float* __restrict__ s0) {
  int bid = blockIdx.x;
  int q = bid >> 3, grp = bid & 7;
  int tid = threadIdx.x;
  int wave = tid >> 6, lane = tid & 63;
  int lb = lane & 15, lg = lane >> 4;
  int b = grp * 16 + lb;
  int jt0 = q * 16 + wave * 2;   // this wave's first jt (of 2)

  // persistent A fragments: 2 jt x 8 kt x 8 halves = 64 VGPRs
  half8 A[2][8];
#pragma unroll
  for (int u = 0; u < 2; ++u)
#pragma unroll
    for (int kt = 0; kt < 8; ++kt)
      A[u][kt] = *(const half8*)(wht + ((size_t)((jt0 + u) * 8 + kt) * 64 + lane) * 8);

  int m0 = jt0 * 4 + lg;          // m for u=0; u=1 is m0+4
  float c0 = s0[(size_t)b * Mc + m0];
  float c1 = s0[(size_t)b * Mc + m0 + 4];

  unsigned* flg = flags + grp * 132;

  for (int t = 0; t < 128; ++t) {
    if (t > 0) {
      if (lane == 0) {
        while (__hip_atomic_load(flg + t, __ATOMIC_ACQUIRE,
                                 __HIP_MEMORY_SCOPE_AGENT) < 4u)
          __builtin_amdgcn_s_sleep(1);
      }
    }
    // B fragments: h[t], all 256 m for this lane's batch
    const __half* hxt = hx + (size_t)t * (Bc * Mc) + (size_t)b * Mc + lg * 8;
    half8 Bf[8];
#pragma unroll
    for (int kt = 0; kt < 8; ++kt)
      Bf[kt] = *(const half8*)(hxt + kt * 32);
    // acc init = XWxP (C-in of MFMA)
    const float* xp = xwxp + ((size_t)t * Bc + b) * G4 + lg * 4;
    f32x4 acc0 = *(const f32x4*)(xp + (size_t)jt0 * 16);
    f32x4 acc1 = *(const f32x4*)(xp + (size_t)(jt0 + 1) * 16);
#pragma unroll
    for (int kt = 0; kt < 8; ++kt) {
      acc0 = __builtin_amdgcn_mfma_f32_16x16x32_f16(A[0][kt], Bf[kt], acc0, 0, 0, 0);
      acc1 = __builtin_amdgcn_mfma_f32_16x16x32_f16(A[1][kt], Bf[kt], acc1, 0, 0, 0);
    }
    // gates: regs 0..3 = (i,f,g,o) for (m, b)
    float i0 = fsig(acc0[0]), f0 = fsig(acc0[1]);
    float g0 = ftanh(acc0[2]), o0 = fsig(acc0[3]);
    c0 = f0 * c0 + i0 * g0;
    float h0v = o0 * ftanh(c0);
    float i1 = fsig(acc1[0]), f1 = fsig(acc1[1]);
    float g1 = ftanh(acc1[2]), o1 = fsig(acc1[3]);
    c1 = f1 * c1 + i1 * g1;
    float h1v = o1 * ftanh(c1);

    size_t ob = (size_t)(t + 1) * (Bc * Mc) + (size_t)b * Mc;
    hx[ob + m0]     = __float2half(h0v);
    hx[ob + m0 + 4] = __float2half(h1v);
    size_t oc = (size_t)t * (Bc * Mc) + (size_t)b * Mc;
    cx[oc + m0]     = __float2half(c0);
    cx[oc + m0 + 4] = __float2half(c1);

    __syncthreads();  // all waves' stores drained (vmcnt) before flag
    if (tid == 0)
      __hip_atomic_fetch_add(flg + t + 1, 1u, __ATOMIC_RELEASE,
                             __HIP_MEMORY_SCOPE_AGENT);
  }
}

// ---------------------------------------------------------------------------
// k_wall2: Wall[t*B+b][u] = sum_k h[t+1][b][k]*Wd[k][u]
//                         + sum_k c[t+1][b][k]*Wd[256+k][u] + bW[u]
// h,c read as fp16 (hx slot t+1 == half2 index 16384 + r*128; cx == r*128).
// ---------------------------------------------------------------------------
__global__ void k_wall2(const __half2* __restrict__ Hx2, const __half2* __restrict__ Cx2,
                        const float* __restrict__ Wd, const float* __restrict__ bW,
                        float* __restrict__ Wall) {
  int r0 = blockIdx.x * 32;
  int wv = __builtin_amdgcn_readfirstlane(threadIdx.x >> 6);
  int lane = threadIdx.x & 63;
  int u2 = lane * 2;
  int rbase = r0 + wv * 8;
  float acc[8][2];
#pragma unroll
  for (int i = 0; i < 8; i++) { acc[i][0] = 0.f; acc[i][1] = 0.f; }
#pragma unroll 2
  for (int k2 = 0; k2 < 128; ++k2) {
    float2 wh0 = *(const float2*)(Wd + (size_t)(2 * k2) * Tc + u2);
    float2 wh1 = *(const float2*)(Wd + (size_t)(2 * k2 + 1) * Tc + u2);
    float2 wc0 = *(const float2*)(Wd + (size_t)(Mc + 2 * k2) * Tc + u2);
    float2 wc1 = *(const float2*)(Wd + (size_t)(Mc + 2 * k2 + 1) * Tc + u2);
#pragma unroll
    for (int i = 0; i < 8; i++) {
      __half2 hv = Hx2[(size_t)(rbase + i) * 128 + 16384 + k2];  // slot t+1
      __half2 cv = Cx2[(size_t)(rbase + i) * 128 + k2];
      float hlo = __low2float(hv), hhi = __high2float(hv);
      float clo = __low2float(cv), chi = __high2float(cv);
      acc[i][0] += hlo * wh0.x + hhi * wh1.x + clo * wc0.x + chi * wc1.x;
      acc[i][1] += hlo * wh0.y + hhi * wh1.y + clo * wc0.y + chi * wc1.y;
    }
  }
  float bw0 = bW[u2], bw1 = bW[u2 + 1];
#pragma unroll
  for (int i = 0; i < 8; i++) {
    float2 o; o.x = acc[i][0] + bw0; o.y = acc[i][1] + bw1;
    *(float2*)(Wall + (size_t)(rbase + i) * Tc + u2) = o;
  }
}

// ---------------------------------------------------------------------------
// k_attn: e -> softmax over n -> out = X * alpha. Block = 2 rows (t,b).
// ---------------------------------------------------------------------------
__global__ void k_attn(const float* __restrict__ Wall, const float* __restrict__ UXT,
                       const float* __restrict__ vd, const float* __restrict__ X,
                       float* __restrict__ out) {
  __shared__ float wl[2][Nc];
  __shared__ float vl[Nc];
  __shared__ float rmax[4], rsum[4];
  int r0 = blockIdx.x * 2;
  int rr = threadIdx.x >> 7, n = threadIdx.x & 127;
  if (threadIdx.x < Nc) vl[threadIdx.x] = vd[threadIdx.x];
  wl[rr][n] = Wall[(size_t)(r0 + rr) * Tc + n];
  __syncthreads();
  int r = r0 + rr;
  int t = r >> 7, b = r & 127;
  const float* uxb = UXT + (size_t)b * Tc * Nc;
  float e = 0.f;
#pragma unroll 4
  for (int u = 0; u < Tc; ++u) {
    float s = wl[rr][u] + uxb[(size_t)u * Nc + n];
    e += ftanh(s) * vl[u];
  }
  float m = e;
#pragma unroll
  for (int off = 32; off > 0; off >>= 1) m = fmaxf(m, __shfl_xor(m, off));
  int wv = threadIdx.x >> 6;
  if ((threadIdx.x & 63) == 0) rmax[wv] = m;
  __syncthreads();
  float mrow = fmaxf(rmax[rr * 2], rmax[rr * 2 + 1]);
  float ex = __expf(e - mrow);
  float s = ex;
#pragma unroll
  for (int off = 32; off > 0; off >>= 1) s += __shfl_xor(s, off);
  if ((threadIdx.x & 63) == 0) rsum[wv] = s;
  __syncthreads();
  float srow = rsum[rr * 2] + rsum[rr * 2 + 1];
  float alpha = ex * frcp(srow);
  size_t xi = ((size_t)b * Tc + t) * Nc + n;
  out[xi] = X[xi] * alpha;
}

extern "C" void kernel_launch(void* const* d_in, const int* in_sizes, int n_in,
                              void* d_out, int out_size, void* d_ws, size_t ws_size,
                              hipStream_t stream) {
  (void)in_sizes; (void)n_in; (void)out_size; (void)ws_size;
  const float* X  = (const float*)d_in[0];
  const float* h0 = (const float*)d_in[1];
  const float* s0 = (const float*)d_in[2];
  const float* Wx = (const float*)d_in[3];
  const float* Wh = (const float*)d_in[4];
  const float* bb = (const float*)d_in[5];
  const float* Wd = (const float*)d_in[6];
  const float* bW = (const float*)d_in[7];
  const float* Ud = (const float*)d_in[8];
  const float* bU = (const float*)d_in[9];
  const float* vd = (const float*)d_in[10];
  // d_in[11] = bv: softmax(x + const) == softmax(x), no effect on output.
  float* out = (float*)d_out;
  float* ws = (float*)d_ws;

  // workspace layout (f32 words unless noted)
  float* UXT  = ws;                          //  2,097,152 f
  float* XWxP = UXT + 2097152;               // 16,777,216 f
  __half* hx  = (__half*)(XWxP + 16777216);  // 129*32768 halves
  __half* cx  = hx + 129 * 32768;            // 128*32768 halves
  float* Wall = (float*)(cx + 128 * 32768);  //  2,097,152 f
  __half* wht = (__half*)(Wall + 2097152);   //   262,144 halves
  unsigned* flags = (unsigned*)(wht + 262144); // 1056 u32
  // total ~96.6 MB

  k_prep<<<513, 256, 0, stream>>>(Wh, h0, wht, hx, flags);
  k_ux<<<Bc, 256, 0, stream>>>(X, Ud, bU, UXT);
  k_xwx2<<<Tc * 8, 256, 0, stream>>>(X, Wx, bb, XWxP);
  k_scan<<<32, 512, 0, stream>>>(wht, XWxP, hx, cx, flags, s0);
  k_wall2<<<(Tc * Bc) / 32, 256, 0, stream>>>((const __half2*)hx, (const __half2*)cx,
                                              Wd, bW, Wall);
  k_attn<<<(Tc * Bc) / 2, 256, 0, stream>>>(Wall, UXT, vd, X, out);
}

// Round 3
// 713.591 us; speedup vs baseline: 3.0306x; 1.6246x over previous
//
#include <hip/hip_runtime.h>
#include <hip/hip_fp16.h>

// Problem dims (fixed)
#define Bc 128   // batch
#define Tc 128   // timesteps
#define Nc 128   // driving series
#define Mc 256   // hidden
#define G4 1024  // 4*M

typedef _Float16 half8 __attribute__((ext_vector_type(8)));
typedef float f32x4 __attribute__((ext_vector_type(4)));

__device__ __forceinline__ float frcp(float x) {
#if __has_builtin(__builtin_amdgcn_rcpf)
  return __builtin_amdgcn_rcpf(x);
#else
  return 1.f / x;
#endif
}
__device__ __forceinline__ float fsig(float x) { return frcp(1.f + __expf(-x)); }
__device__ __forceinline__ float ftanh(float x) {
  float t = __expf(2.f * x);
  return 1.f - 2.f * frcp(t + 1.f);
}

// bypassing (coherence-point) memory ops for cross-XCD producer/consumer
__device__ __forceinline__ f32x4 load_x4_cc(const void* p) {
  f32x4 r;
  asm volatile("global_load_dwordx4 %0, %1, off sc0 sc1" : "=v"(r) : "v"(p));
  return r;
}
__device__ __forceinline__ void store_h_cc(void* p, unsigned short v) {
  asm volatile("global_store_short %0, %1, off sc0 sc1" :: "v"(p), "v"((unsigned)v) : "memory");
}

// ---------------------------------------------------------------------------
// k_prep: (a) pack Wh into fp16 MFMA A-fragments with gate-interleaved column
// permutation j' = 4*mcol + g; (b) zero flags; (c) hx[0] = fp16(h0).
// ---------------------------------------------------------------------------
__global__ void k_prep(const float* __restrict__ Wh, const float* __restrict__ h0,
                       __half* __restrict__ wht, __half* __restrict__ hx,
                       unsigned* __restrict__ flags) {
  int bid = blockIdx.x;
  if (bid < 512) {
    int i = bid * 256 + threadIdx.x;       // u32 index in [0, 131072)
    int jt = i >> 11;
    int rem = i & 2047;
    int kt = rem >> 8;
    int rem2 = rem & 255;
    int lane = rem2 >> 2;
    int r2 = rem2 & 3;
    int jp = jt * 16 + (lane & 15);        // permuted col j'
    int g = jp & 3, mcol = jp >> 2;
    int j = g * 256 + mcol;                // original Wh column
    int mk0 = kt * 32 + (lane >> 4) * 8 + 2 * r2;
    wht[(size_t)i * 2]     = __float2half(Wh[(size_t)mk0 * G4 + j]);
    wht[(size_t)i * 2 + 1] = __float2half(Wh[(size_t)(mk0 + 1) * G4 + j]);
  } else {
    for (int i = threadIdx.x; i < 8 * 4096; i += 256) flags[i] = 0u;
    for (int i = threadIdx.x; i < Bc * Mc; i += 256) hx[i] = __float2half(h0[i]);
  }
}

// ---------------------------------------------------------------------------
// k_ux: PX[b][u][n] = exp(2*(sum_t X[b][t][n]*Ud[t][u] + bU[u]))
// (t-invariant factor of tanh's exp in the attention score)
// ---------------------------------------------------------------------------
__global__ void k_ux(const float* __restrict__ X, const float* __restrict__ Ud,
                     const float* __restrict__ bU, float* __restrict__ PX) {
  __shared__ float Xl[Tc][Nc];  // 64KB
  int b = blockIdx.x;
  const float* Xb = X + (size_t)b * Tc * Nc;
  for (int i = threadIdx.x; i < Tc * Nc; i += 256) Xl[i >> 7][i & 127] = Xb[i];
  __syncthreads();
  int n = threadIdx.x & 127;
  int uh = __builtin_amdgcn_readfirstlane(threadIdx.x >> 7);
  for (int u0 = uh * 64; u0 < uh * 64 + 64; u0 += 8) {
    float acc[8];
#pragma unroll
    for (int i = 0; i < 8; i++) acc[i] = 0.f;
    for (int tt = 0; tt < Tc; ++tt) {
      float xv = Xl[tt][n];
#pragma unroll
      for (int i = 0; i < 8; i++) acc[i] += xv * Ud[tt * Tc + u0 + i];
    }
#pragma unroll
    for (int i = 0; i < 8; i++)
      PX[((size_t)b * Tc + (u0 + i)) * Nc + n] = __expf(2.f * (acc[i] + bU[u0 + i]));
  }
}

// ---------------------------------------------------------------------------
// k_xwx2: XWxP[t][b][j'] with j' = 4m+g. grid 512 = t(128) x bq(4), 256 thr.
// 32 rows (same t, 32 consecutive b) per block to amortize Wx reads.
// ---------------------------------------------------------------------------
__global__ __launch_bounds__(256, 2)
void k_xwx2(const float* __restrict__ X, const float* __restrict__ Wx,
            const float* __restrict__ bias, float* __restrict__ XWxP) {
  __shared__ float xl[32][Nc];  // 16KB
  int t = blockIdx.x >> 2;
  int b0 = (blockIdx.x & 3) * 32;
  for (int i = threadIdx.x; i < 32 * Nc; i += 256) {
    int row = i >> 7, n = i & 127;
    xl[row][n] = X[(size_t)(b0 + row) * Tc * Nc + (size_t)t * Nc + n];
  }
  __syncthreads();
  int m = threadIdx.x;
  float acc[32][4];
#pragma unroll
  for (int i = 0; i < 32; i++)
#pragma unroll
    for (int g = 0; g < 4; g++) acc[i][g] = 0.f;
  for (int n = 0; n < Nc; ++n) {
    float wi = Wx[(size_t)n * G4 + m];
    float wf = Wx[(size_t)n * G4 + 256 + m];
    float wg = Wx[(size_t)n * G4 + 512 + m];
    float wo = Wx[(size_t)n * G4 + 768 + m];
#pragma unroll
    for (int i = 0; i < 32; i++) {
      float xv = xl[i][n];
      acc[i][0] += xv * wi; acc[i][1] += xv * wf;
      acc[i][2] += xv * wg; acc[i][3] += xv * wo;
    }
  }
  float bi = bias[m], bf = bias[256 + m], bg = bias[512 + m], bo = bias[768 + m];
#pragma unroll
  for (int i = 0; i < 32; i++) {
    float4 o;
    o.x = acc[i][0] + bi; o.y = acc[i][1] + bf;
    o.z = acc[i][2] + bg; o.w = acc[i][3] + bo;
    *(float4*)(XWxP + ((size_t)t * Bc + b0 + i) * G4 + m * 4) = o;
  }
}

// ---------------------------------------------------------------------------
// k_scan: persistent LSTM scan, 32 blocks x 512 threads, fence-free sync.
// bid = q*8 + grp. h stored write-through (sc0 sc1) -> vmcnt -> barrier ->
// RELAXED agent fetch_add; consumers RELAXED-poll + sc0sc1 data loads.
// Flags spaced 64B; no cache-wide maintenance ops anywhere.
// ---------------------------------------------------------------------------
__global__ __launch_bounds__(512, 2)
void k_scan(const __half* __restrict__ wht, const float* __restrict__ xwxp,
            __half* __restrict__ hx, __half* __restrict__ cx,
            unsigned* __restrict__ flags, const float* __restrict__ s0) {
  int bid = blockIdx.x;
  int q = bid >> 3, grp = bid & 7;
  int tid = threadIdx.x;
  int wave = tid >> 6, lane = tid & 63;
  int lb = lane & 15, lg = lane >> 4;
  int b = grp * 16 + lb;
  int jt0 = q * 16 + wave * 2;

  // persistent A fragments: 64 VGPRs
  half8 A[2][8];
#pragma unroll
  for (int u = 0; u < 2; ++u)
#pragma unroll
    for (int kt = 0; kt < 8; ++kt)
      A[u][kt] = *(const half8*)(wht + ((size_t)((jt0 + u) * 8 + kt) * 64 + lane) * 8);

  int m0 = jt0 * 4 + lg;
  float c0 = s0[(size_t)b * Mc + m0];
  float c1 = s0[(size_t)b * Mc + m0 + 4];

  unsigned* flg = flags + grp * 4096;   // slot t at flg[t*16] (64B apart)

  for (int t = 0; t < 128; ++t) {
    // acc init (XWxP) — independent of the flag, issue early
    const float* xp = xwxp + ((size_t)t * Bc + b) * G4 + lg * 4;
    f32x4 acc0 = *(const f32x4*)(xp + (size_t)jt0 * 16);
    f32x4 acc1 = *(const f32x4*)(xp + (size_t)(jt0 + 1) * 16);

    if (t > 0 && lane == 0) {
      while (__hip_atomic_load(flg + t * 16, __ATOMIC_RELAXED,
                               __HIP_MEMORY_SCOPE_AGENT) < 4u) {}
    }
    // B fragments: h[t] via coherence-point loads
    const __half* hxt = hx + (size_t)t * (Bc * Mc) + (size_t)b * Mc + lg * 8;
    f32x4 braw[8];
#pragma unroll
    for (int kt = 0; kt < 8; ++kt)
      braw[kt] = load_x4_cc(hxt + kt * 32);
    asm volatile("s_waitcnt vmcnt(0)" ::: "memory");
    __builtin_amdgcn_sched_barrier(0);

#pragma unroll
    for (int kt = 0; kt < 8; ++kt) {
      half8 Bf = __builtin_bit_cast(half8, braw[kt]);
      acc0 = __builtin_amdgcn_mfma_f32_16x16x32_f16(A[0][kt], Bf, acc0, 0, 0, 0);
      acc1 = __builtin_amdgcn_mfma_f32_16x16x32_f16(A[1][kt], Bf, acc1, 0, 0, 0);
    }
    // gates: regs 0..3 = (i,f,g,o) for (m, b)
    float i0 = fsig(acc0[0]), f0 = fsig(acc0[1]);
    float g0 = ftanh(acc0[2]), o0 = fsig(acc0[3]);
    c0 = f0 * c0 + i0 * g0;
    float h0v = o0 * ftanh(c0);
    float i1 = fsig(acc1[0]), f1 = fsig(acc1[1]);
    float g1 = ftanh(acc1[2]), o1 = fsig(acc1[3]);
    c1 = f1 * c1 + i1 * g1;
    float h1v = o1 * ftanh(c1);

    __half* hob = hx + (size_t)(t + 1) * (Bc * Mc) + (size_t)b * Mc;
    store_h_cc(hob + m0,     __half_as_ushort(__float2half(h0v)));
    store_h_cc(hob + m0 + 4, __half_as_ushort(__float2half(h1v)));
    asm volatile("s_waitcnt vmcnt(0)" ::: "memory");
    __syncthreads();
    if (tid == 0)
      __hip_atomic_fetch_add(flg + (t + 1) * 16, 1u, __ATOMIC_RELAXED,
                             __HIP_MEMORY_SCOPE_AGENT);
    // c only feeds k_wall2 (next kernel) — lazy, normal stores
    __half* cob = cx + (size_t)t * (Bc * Mc) + (size_t)b * Mc;
    cob[m0]     = __float2half(c0);
    cob[m0 + 4] = __float2half(c1);
  }
}

// ---------------------------------------------------------------------------
// k_wall2: Wall[t*B+b][u] = [h;c] @ Wd + bW (h,c as fp16)
// ---------------------------------------------------------------------------
__global__ void k_wall2(const __half2* __restrict__ Hx2, const __half2* __restrict__ Cx2,
                        const float* __restrict__ Wd, const float* __restrict__ bW,
                        float* __restrict__ Wall) {
  int r0 = blockIdx.x * 32;
  int wv = __builtin_amdgcn_readfirstlane(threadIdx.x >> 6);
  int lane = threadIdx.x & 63;
  int u2 = lane * 2;
  int rbase = r0 + wv * 8;
  float acc[8][2];
#pragma unroll
  for (int i = 0; i < 8; i++) { acc[i][0] = 0.f; acc[i][1] = 0.f; }
#pragma unroll 2
  for (int k2 = 0; k2 < 128; ++k2) {
    float2 wh0 = *(const float2*)(Wd + (size_t)(2 * k2) * Tc + u2);
    float2 wh1 = *(const float2*)(Wd + (size_t)(2 * k2 + 1) * Tc + u2);
    float2 wc0 = *(const float2*)(Wd + (size_t)(Mc + 2 * k2) * Tc + u2);
    float2 wc1 = *(const float2*)(Wd + (size_t)(Mc + 2 * k2 + 1) * Tc + u2);
#pragma unroll
    for (int i = 0; i < 8; i++) {
      __half2 hv = Hx2[(size_t)(rbase + i) * 128 + 16384 + k2];  // slot t+1
      __half2 cv = Cx2[(size_t)(rbase + i) * 128 + k2];
      float hlo = __low2float(hv), hhi = __high2float(hv);
      float clo = __low2float(cv), chi = __high2float(cv);
      acc[i][0] += hlo * wh0.x + hhi * wh1.x + clo * wc0.x + chi * wc1.x;
      acc[i][1] += hlo * wh0.y + hhi * wh1.y + clo * wc0.y + chi * wc1.y;
    }
  }
  float bw0 = bW[u2], bw1 = bW[u2 + 1];
#pragma unroll
  for (int i = 0; i < 8; i++) {
    float2 o; o.x = acc[i][0] + bw0; o.y = acc[i][1] + bw1;
    *(float2*)(Wall + (size_t)(rbase + i) * Tc + u2) = o;
  }
}

// ---------------------------------------------------------------------------
// k_attn: logits_n = sum_u (-2 v_u) / (A_u * P_un + 1)   (Σv dropped: softmax
// is shift-invariant). Block = 4 t-rows of one b; P reused across the 4 rows.
// grid 4096 = b(128) x tq(32), 128 threads (= n).
// ---------------------------------------------------------------------------
__global__ void k_attn(const float* __restrict__ Wall, const float* __restrict__ PX,
                       const float* __restrict__ vd, const float* __restrict__ X,
                       float* __restrict__ out) {
  __shared__ float4 av[Nc];      // av[u] = exp(2*wall[t0..t0+3][u])
  __shared__ float v2s[Nc];
  __shared__ float wred[2][4];
  int b = blockIdx.x & 127, tq = blockIdx.x >> 7;
  int n = threadIdx.x;           // 0..127
  int wv = n >> 6;
  float4 a;
  a.x = __expf(2.f * Wall[((size_t)(tq * 4 + 0) * Bc + b) * Tc + n]);
  a.y = __expf(2.f * Wall[((size_t)(tq * 4 + 1) * Bc + b) * Tc + n]);
  a.z = __expf(2.f * Wall[((size_t)(tq * 4 + 2) * Bc + b) * Tc + n]);
  a.w = __expf(2.f * Wall[((size_t)(tq * 4 + 3) * Bc + b) * Tc + n]);
  av[n] = a;
  v2s[n] = -2.f * vd[n];
  __syncthreads();
  const float* Pb = PX + (size_t)b * Tc * Nc;
  float e0 = 0.f, e1 = 0.f, e2 = 0.f, e3 = 0.f;
#pragma unroll 4
  for (int u = 0; u < Tc; ++u) {
    float P = Pb[(size_t)u * Nc + n];
    float4 au = av[u];
    float v2 = v2s[u];
    e0 = fmaf(v2, frcp(fmaf(au.x, P, 1.f)), e0);
    e1 = fmaf(v2, frcp(fmaf(au.y, P, 1.f)), e1);
    e2 = fmaf(v2, frcp(fmaf(au.z, P, 1.f)), e2);
    e3 = fmaf(v2, frcp(fmaf(au.w, P, 1.f)), e3);
  }
  float e[4] = {e0, e1, e2, e3};
  float M[4], S[4], ex[4];
#pragma unroll
  for (int k = 0; k < 4; ++k) {
    float m = e[k];
#pragma unroll
    for (int off = 32; off > 0; off >>= 1) m = fmaxf(m, __shfl_xor(m, off));
    if ((n & 63) == 0) wred[wv][k] = m;
  }
  __syncthreads();
#pragma unroll
  for (int k = 0; k < 4; ++k) M[k] = fmaxf(wred[0][k], wred[1][k]);
  __syncthreads();
#pragma unroll
  for (int k = 0; k < 4; ++k) {
    ex[k] = __expf(e[k] - M[k]);
    float s = ex[k];
#pragma unroll
    for (int off = 32; off > 0; off >>= 1) s += __shfl_xor(s, off);
    if ((n & 63) == 0) wred[wv][k] = s;
  }
  __syncthreads();
#pragma unroll
  for (int k = 0; k < 4; ++k) S[k] = wred[0][k] + wred[1][k];
#pragma unroll
  for (int k = 0; k < 4; ++k) {
    int t = tq * 4 + k;
    size_t xi = ((size_t)b * Tc + t) * Nc + n;
    out[xi] = X[xi] * (ex[k] * frcp(S[k]));
  }
}

extern "C" void kernel_launch(void* const* d_in, const int* in_sizes, int n_in,
                              void* d_out, int out_size, void* d_ws, size_t ws_size,
                              hipStream_t stream) {
  (void)in_sizes; (void)n_in; (void)out_size; (void)ws_size;
  const float* X  = (const float*)d_in[0];
  const float* h0 = (const float*)d_in[1];
  const float* s0 = (const float*)d_in[2];
  const float* Wx = (const float*)d_in[3];
  const float* Wh = (const float*)d_in[4];
  const float* bb = (const float*)d_in[5];
  const float* Wd = (const float*)d_in[6];
  const float* bW = (const float*)d_in[7];
  const float* Ud = (const float*)d_in[8];
  const float* bU = (const float*)d_in[9];
  const float* vd = (const float*)d_in[10];
  // d_in[11] = bv: softmax(x + const) == softmax(x), no effect on output.
  float* out = (float*)d_out;
  float* ws = (float*)d_ws;

  float* PX   = ws;                          //  2,097,152 f
  float* XWxP = PX + 2097152;                // 16,777,216 f
  __half* hx  = (__half*)(XWxP + 16777216);  // 129*32768 halves
  __half* cx  = hx + 129 * 32768;            // 128*32768 halves
  float* Wall = (float*)(cx + 128 * 32768);  //  2,097,152 f
  __half* wht = (__half*)(Wall + 2097152);   //   262,144 halves
  unsigned* flags = (unsigned*)(wht + 262144); // 8*4096 u32
  // total ~101 MB

  k_prep<<<513, 256, 0, stream>>>(Wh, h0, wht, hx, flags);
  k_ux<<<Bc, 256, 0, stream>>>(X, Ud, bU, PX);
  k_xwx2<<<Tc * 4, 256, 0, stream>>>(X, Wx, bb, XWxP);
  k_scan<<<32, 512, 0, stream>>>(wht, XWxP, hx, cx, flags, s0);
  k_wall2<<<(Tc * Bc) / 32, 256, 0, stream>>>((const __half2*)hx, (const __half2*)cx,
                                              Wd, bW, Wall);
  k_attn<<<Bc * 32, 128, 0, stream>>>(Wall, PX, vd, X, out);
}